// Round 6
// baseline (594.609 us; speedup 1.0000x reference)
//
#include <hip/hip_runtime.h>
#include <hip/hip_bf16.h>
#include <stdint.h>

typedef __attribute__((ext_vector_type(8))) short short8;
typedef __attribute__((ext_vector_type(4))) float f32x4;

#define CH 64
#define NC 128   /* 8192 / CH */

__device__ __forceinline__ unsigned short f2bf(float f) {
  union { float f; unsigned u; } x; x.f = f;
  unsigned u = x.u;
  u = (u + 0x7fffu + ((u >> 16) & 1u)) >> 16;
  return (unsigned short)u;
}
__device__ __forceinline__ float bf2f(unsigned u16) {
  union { unsigned u; float f; } x; x.u = u16 << 16;
  return x.f;
}

#define GLOAD_LDS16(gptr, lptr) \
  __builtin_amdgcn_global_load_lds((const __attribute__((address_space(1))) void*)(gptr), \
                                   (__attribute__((address_space(3))) void*)(lptr), 16, 0, 0)

// ---------------- f32 -> bf16 convert (vectorized) ----------------
__global__ void k_f32_to_bf16(const float* __restrict__ src, unsigned short* __restrict__ dst, int n4) {
  int i = blockIdx.x * blockDim.x + threadIdx.x;
  if (i >= n4) return;
  float4 f = reinterpret_cast<const float4*>(src)[i];
  ushort4 o = make_ushort4(f2bf(f.x), f2bf(f.y), f2bf(f.z), f2bf(f.w));
  reinterpret_cast<ushort4*>(dst)[i] = o;
}

// ---------------- GEMM1: hg = X @ W_hg^T, dual-B (h and gate halves) ---------
// Epilogue fuses the MinGRU nonlinearity, writes packed (a|v<<16) bf16 pairs,
// AND computes the per-chunk scan aggregates (scanA fused): with CH=64 each
// wave's 64 output rows are exactly one chunk, so the (A,V) chunk aggregate is
// an in-lane fold over r, an ordered shfl_xor butterfly over q, and a
// sequential fold over f.
__global__ __launch_bounds__(256, 3) void k_gemm1(
    const unsigned short* __restrict__ Xb,
    const unsigned short* __restrict__ Wb,
    uint32_t* __restrict__ avArr,
    float* __restrict__ Acar, float* __restrict__ Vcar)
{
  __shared__ unsigned short As[128 * 64];
  __shared__ unsigned short Bs0[128 * 64];
  __shared__ unsigned short Bs1[128 * 64];

  const int m0 = blockIdx.y * 128;
  const int i0 = blockIdx.x * 128;
  const int tid = threadIdx.x;
  const int lane = tid & 63;
  const int wave = tid >> 6;
  const int wm = (wave >> 1) * 64;
  const int wn = (wave & 1) * 64;
  const int srow = tid >> 3;         // 0..31
  const int scol = (tid & 7) * 8;    // element col in [0,64)

  f32x4 acc0[4][4], acc1[4][4];
#pragma unroll
  for (int f = 0; f < 4; ++f)
#pragma unroll
    for (int g = 0; g < 4; ++g) {
      acc0[f][g] = f32x4{0.f, 0.f, 0.f, 0.f};
      acc1[f][g] = f32x4{0.f, 0.f, 0.f, 0.f};
    }

  for (int k0 = 0; k0 < 512; k0 += 64) {
    __syncthreads();   // all waves done reading previous tile
#pragma unroll
    for (int j = 0; j < 4; ++j) {
      int row = j * 32 + srow;
      GLOAD_LDS16(Xb + (size_t)(m0 + row) * 512 + k0 + scol, As + row * 64 + scol);
    }
#pragma unroll
    for (int j = 0; j < 4; ++j) {
      int row = j * 32 + srow;
      GLOAD_LDS16(Wb + (size_t)(i0 + row) * 512 + k0 + scol, Bs0 + row * 64 + scol);
    }
#pragma unroll
    for (int j = 0; j < 4; ++j) {
      int row = j * 32 + srow;
      GLOAD_LDS16(Wb + (size_t)(1024 + i0 + row) * 512 + k0 + scol, Bs1 + row * 64 + scol);
    }
    __syncthreads();   // compiler drains vmcnt before barrier -> LDS ready

#pragma unroll
    for (int kk = 0; kk < 2; ++kk) {
      const int kof = kk * 32 + (lane >> 4) * 8;
      const int rl = lane & 15;
      short8 av[4], b0[4], b1[4];
#pragma unroll
      for (int f = 0; f < 4; ++f)
        av[f] = *(const short8*)(As + (wm + f * 16 + rl) * 64 + kof);
#pragma unroll
      for (int g = 0; g < 4; ++g) {
        b0[g] = *(const short8*)(Bs0 + (wn + g * 16 + rl) * 64 + kof);
        b1[g] = *(const short8*)(Bs1 + (wn + g * 16 + rl) * 64 + kof);
      }
#pragma unroll
      for (int f = 0; f < 4; ++f)
#pragma unroll
        for (int g = 0; g < 4; ++g) {
          acc0[f][g] = __builtin_amdgcn_mfma_f32_16x16x32_bf16(av[f], b0[g], acc0[f][g], 0, 0, 0);
          acc1[f][g] = __builtin_amdgcn_mfma_f32_16x16x32_bf16(av[f], b1[g], acc1[f][g], 0, 0, 0);
        }
    }
  }

  // ---- fused epilogue: nonlinearity + packed store + chunk-aggregate ----
  // C/D layout: col = lane&15, row = (lane>>4)*4 + reg
  const int rl = lane & 15;
  const int q  = lane >> 4;
  const int mb = m0 + wm;             // wave row base == chunk base (CH=64)
  const int b  = mb >> 13;            // /8192
  const int c  = (mb & 8191) >> 6;    // /64

#pragma unroll
  for (int g = 0; g < 4; ++g) {
    const int i = i0 + wn + g * 16 + rl;
    float Achunk = 1.f, Vchunk = 0.f;
#pragma unroll
    for (int f = 0; f < 4; ++f) {
      float Aseg = 1.f, Vseg = 0.f;
#pragma unroll
      for (int r = 0; r < 4; ++r) {
        float h    = acc0[f][g][r];
        float gate = acc1[f][g][r];
        float e  = __expf(gate);
        float ac = __builtin_amdgcn_rcpf(1.f + e);   // sigmoid(-gate)
        float z  = e * ac;                           // sigmoid(gate)
        float gg;
        if (h >= 0.f) gg = h + 0.5f;
        else { float eh = __expf(h); gg = eh * __builtin_amdgcn_rcpf(1.f + eh); }
        float v = z * gg;
        int m = mb + f * 16 + q * 4 + r;
        avArr[(size_t)m * 1024 + i] = (uint32_t)f2bf(ac) | ((uint32_t)f2bf(v) << 16);
        // in-lane ordered fold over r (rows q*4+r ascending)
        Vseg = Vseg * ac + v;
        Aseg = Aseg * ac;
      }
      // ordered butterfly over q: step 16 (q^1), then step 32 (q^2)
      {
        float Ap = __shfl_xor(Aseg, 16);
        float Vp = __shfl_xor(Vseg, 16);
        if (q & 1) { Vseg = Vp * Aseg + Vseg; Aseg = Ap * Aseg; }
        else       { Vseg = Vseg * Ap + Vp;   Aseg = Aseg * Ap; }
      }
      {
        float Ap = __shfl_xor(Aseg, 32);
        float Vp = __shfl_xor(Vseg, 32);
        if (q & 2) { Vseg = Vp * Aseg + Vseg; Aseg = Ap * Aseg; }
        else       { Vseg = Vseg * Ap + Vp;   Aseg = Aseg * Ap; }
      }
      // sequential fold over f (rows f*16.. ascending)
      Vchunk = Vchunk * Aseg + Vseg;
      Achunk = Achunk * Aseg;
    }
    if (lane < 16) {
      size_t co = ((size_t)b * NC + c) * 1024 + i;
      Acar[co] = Achunk;
      Vcar[co] = Vchunk;
    }
  }
}

// ---------------- scan phase B: sequential carry combine over chunks ----------
__global__ void k_scanB(const float* __restrict__ hidden,
                        const float* __restrict__ Acar, const float* __restrict__ Vcar,
                        float* __restrict__ Hstart)
{
  int t = blockIdx.x * blockDim.x + threadIdx.x;  // 0..4095
  int b = t >> 10, i = t & 1023;
  float H = hidden[(size_t)b * 1024 + i];
  for (int c = 0; c < NC; ++c) {
    size_t o = ((size_t)b * NC + c) * 1024 + i;
    Hstart[o] = H;
    H = fmaf(Acar[o], H, Vcar[o]);
  }
}

// ---------------- scan phase C: re-scan with correct H, emit h_all (bf16) -----
__global__ void k_scanC(const uint32_t* __restrict__ av,
                        const float* __restrict__ Hstart,
                        unsigned short* __restrict__ hAll, float* __restrict__ nextH)
{
  int c = blockIdx.x & (NC - 1);
  int b = blockIdx.x >> 7;  // NC=128
  size_t base4 = (((size_t)b * 8192 + (size_t)c * CH) * 1024) / 4 + threadIdx.x;
  size_t ho = (((size_t)b * NC + c) * 1024) / 4 + threadIdx.x;
  float4 H = reinterpret_cast<const float4*>(Hstart)[ho];
#pragma unroll 4
  for (int t = 0; t < CH; ++t) {
    uint4 u = reinterpret_cast<const uint4*>(av)[base4 + (size_t)t * 256];
    H.x = fmaf(bf2f(u.x & 0xffffu), H.x, bf2f(u.x >> 16));
    H.y = fmaf(bf2f(u.y & 0xffffu), H.y, bf2f(u.y >> 16));
    H.z = fmaf(bf2f(u.z & 0xffffu), H.z, bf2f(u.z >> 16));
    H.w = fmaf(bf2f(u.w & 0xffffu), H.w, bf2f(u.w >> 16));
    ushort4 o = make_ushort4(f2bf(H.x), f2bf(H.y), f2bf(H.z), f2bf(H.w));
    reinterpret_cast<ushort4*>(hAll)[base4 + (size_t)t * 256] = o;
  }
  if (c == NC - 1)
    reinterpret_cast<float4*>(nextH)[(size_t)b * 256 + threadIdx.x] = H;
}

// ---------------- GEMM2: out = h_all @ W_out^T ----------------
__global__ __launch_bounds__(256, 3) void k_gemm2(
    const unsigned short* __restrict__ Ab,   // 32768 x 1024 bf16
    const unsigned short* __restrict__ Bb,   // 512 x 1024 bf16
    float* __restrict__ out)                 // 32768 x 512 f32
{
  __shared__ unsigned short As[128 * 64];
  __shared__ unsigned short Bs[128 * 64];

  const int m0 = blockIdx.y * 128;
  const int n0 = blockIdx.x * 128;
  const int tid = threadIdx.x;
  const int lane = tid & 63;
  const int wave = tid >> 6;
  const int wm = (wave >> 1) * 64;
  const int wn = (wave & 1) * 64;
  const int srow = tid >> 3;
  const int scol = (tid & 7) * 8;

  f32x4 acc[4][4];
#pragma unroll
  for (int f = 0; f < 4; ++f)
#pragma unroll
    for (int g = 0; g < 4; ++g) acc[f][g] = f32x4{0.f, 0.f, 0.f, 0.f};

  for (int k0 = 0; k0 < 1024; k0 += 64) {
    __syncthreads();
#pragma unroll
    for (int j = 0; j < 4; ++j) {
      int row = j * 32 + srow;
      GLOAD_LDS16(Ab + (size_t)(m0 + row) * 1024 + k0 + scol, As + row * 64 + scol);
    }
#pragma unroll
    for (int j = 0; j < 4; ++j) {
      int row = j * 32 + srow;
      GLOAD_LDS16(Bb + (size_t)(n0 + row) * 1024 + k0 + scol, Bs + row * 64 + scol);
    }
    __syncthreads();

#pragma unroll
    for (int kk = 0; kk < 2; ++kk) {
      const int kof = kk * 32 + (lane >> 4) * 8;
      const int rl = lane & 15;
      short8 av[4], bv[4];
#pragma unroll
      for (int f = 0; f < 4; ++f)
        av[f] = *(const short8*)(As + (wm + f * 16 + rl) * 64 + kof);
#pragma unroll
      for (int g = 0; g < 4; ++g)
        bv[g] = *(const short8*)(Bs + (wn + g * 16 + rl) * 64 + kof);
#pragma unroll
      for (int f = 0; f < 4; ++f)
#pragma unroll
        for (int g = 0; g < 4; ++g)
          acc[f][g] = __builtin_amdgcn_mfma_f32_16x16x32_bf16(av[f], bv[g], acc[f][g], 0, 0, 0);
    }
  }

  const int rl = lane & 15;
  const int rr = (lane >> 4) * 4;
#pragma unroll
  for (int f = 0; f < 4; ++f)
#pragma unroll
    for (int g = 0; g < 4; ++g)
#pragma unroll
      for (int r = 0; r < 4; ++r) {
        int m = m0 + wm + f * 16 + rr + r;
        int n = n0 + wn + g * 16 + rl;
        out[(size_t)m * 512 + n] = acc[f][g][r];
      }
}

// ---------------- driver ----------------
extern "C" void kernel_launch(void* const* d_in, const int* in_sizes, int n_in,
                              void* d_out, int out_size, void* d_ws, size_t ws_size,
                              hipStream_t stream) {
  const float* X      = (const float*)d_in[0];
  const float* hidden = (const float*)d_in[1];
  const float* W_hg   = (const float*)d_in[2];
  const float* W_out  = (const float*)d_in[3];

  float* out   = (float*)d_out;                    // (4,8192,512) f32
  float* nextH = out + (size_t)32768 * 512;        // (4,1,1024) f32

  char* ws = (char*)d_ws;
  size_t off = 0;
  auto alloc = [&](size_t bytes) -> void* {
    void* p = ws + off;
    off = (off + bytes + 255) & ~(size_t)255;
    return p;
  };
  unsigned short* Xb    = (unsigned short*)alloc(32768ULL * 512 * 2);
  unsigned short* Whgb  = (unsigned short*)alloc(2048ULL * 512 * 2);
  unsigned short* Woutb = (unsigned short*)alloc(512ULL * 1024 * 2);
  unsigned short* hAll  = (unsigned short*)alloc(32768ULL * 1024 * 2);
  float*    Acar   = (float*)alloc(4ULL * NC * 1024 * 4);
  float*    Vcar   = (float*)alloc(4ULL * NC * 1024 * 4);
  float*    Hstart = (float*)alloc(4ULL * NC * 1024 * 4);
  uint32_t* avArr  = (uint32_t*)alloc(32768ULL * 1024 * 4);

  k_f32_to_bf16<<<16384, 256, 0, stream>>>(X, Xb, 16777216 / 4);
  k_f32_to_bf16<<<1024, 256, 0, stream>>>(W_hg, Whgb, 1048576 / 4);
  k_f32_to_bf16<<<512, 256, 0, stream>>>(W_out, Woutb, 524288 / 4);

  dim3 g1(8, 256);
  k_gemm1<<<g1, 256, 0, stream>>>(Xb, Whgb, avArr, Acar, Vcar);

  k_scanB<<<16, 256, 0, stream>>>(hidden, Acar, Vcar, Hstart);
  k_scanC<<<4 * NC, 256, 0, stream>>>(avArr, Hstart, hAll, nextH);

  dim3 g2(4, 256);
  k_gemm2<<<g2, 256, 0, stream>>>(hAll, Woutb, out);
}

// Round 7
// 329.362 us; speedup vs baseline: 1.8053x; 1.8053x over previous
//
#include <hip/hip_runtime.h>
#include <hip/hip_bf16.h>
#include <stdint.h>

typedef __attribute__((ext_vector_type(8))) short short8;
typedef __attribute__((ext_vector_type(4))) float f32x4;

#define CH 64
#define NC 128   /* 8192 / CH */

__device__ __forceinline__ unsigned short f2bf(float f) {
  union { float f; unsigned u; } x; x.f = f;
  unsigned u = x.u;
  u = (u + 0x7fffu + ((u >> 16) & 1u)) >> 16;
  return (unsigned short)u;
}
__device__ __forceinline__ float bf2f(unsigned u16) {
  union { unsigned u; float f; } x; x.u = u16 << 16;
  return x.f;
}

#define GLOAD_LDS16(gptr, lptr) \
  __builtin_amdgcn_global_load_lds((const __attribute__((address_space(1))) void*)(gptr), \
                                   (__attribute__((address_space(3))) void*)(lptr), 16, 0, 0)

// ---------------- f32 -> bf16 convert (vectorized) ----------------
__global__ void k_f32_to_bf16(const float* __restrict__ src, unsigned short* __restrict__ dst, int n4) {
  int i = blockIdx.x * blockDim.x + threadIdx.x;
  if (i >= n4) return;
  float4 f = reinterpret_cast<const float4*>(src)[i];
  ushort4 o = make_ushort4(f2bf(f.x), f2bf(f.y), f2bf(f.z), f2bf(f.w));
  reinterpret_cast<ushort4*>(dst)[i] = o;
}

// ---------------- GEMM1: hg = X @ W_hg^T, dual-B (h and gate halves) ---------
// Epilogue fuses the MinGRU nonlinearity, writes packed (a|v<<16) bf16 pairs,
// AND computes the per-chunk scan aggregates (scanA fused).
// NOTE: __launch_bounds__(256,2) is REQUIRED — acc0+acc1 = 128 regs must fit
// the unified VGPR+AGPR file. (256,3) caps at 170 and spills accumulators to
// scratch: measured +1.3 GB HBM traffic, MfmaUtil 21->7.7%, 2.7x slower (r6).
__global__ __launch_bounds__(256, 2) void k_gemm1(
    const unsigned short* __restrict__ Xb,
    const unsigned short* __restrict__ Wb,
    uint32_t* __restrict__ avArr,
    float* __restrict__ Acar, float* __restrict__ Vcar)
{
  __shared__ unsigned short As[128 * 64];
  __shared__ unsigned short Bs0[128 * 64];
  __shared__ unsigned short Bs1[128 * 64];

  const int m0 = blockIdx.y * 128;
  const int i0 = blockIdx.x * 128;
  const int tid = threadIdx.x;
  const int lane = tid & 63;
  const int wave = tid >> 6;
  const int wm = (wave >> 1) * 64;
  const int wn = (wave & 1) * 64;
  const int srow = tid >> 3;         // 0..31
  const int scol = (tid & 7) * 8;    // element col in [0,64)

  f32x4 acc0[4][4], acc1[4][4];
#pragma unroll
  for (int f = 0; f < 4; ++f)
#pragma unroll
    for (int g = 0; g < 4; ++g) {
      acc0[f][g] = f32x4{0.f, 0.f, 0.f, 0.f};
      acc1[f][g] = f32x4{0.f, 0.f, 0.f, 0.f};
    }

  for (int k0 = 0; k0 < 512; k0 += 64) {
    __syncthreads();   // all waves done reading previous tile
#pragma unroll
    for (int j = 0; j < 4; ++j) {
      int row = j * 32 + srow;
      GLOAD_LDS16(Xb + (size_t)(m0 + row) * 512 + k0 + scol, As + row * 64 + scol);
    }
#pragma unroll
    for (int j = 0; j < 4; ++j) {
      int row = j * 32 + srow;
      GLOAD_LDS16(Wb + (size_t)(i0 + row) * 512 + k0 + scol, Bs0 + row * 64 + scol);
    }
#pragma unroll
    for (int j = 0; j < 4; ++j) {
      int row = j * 32 + srow;
      GLOAD_LDS16(Wb + (size_t)(1024 + i0 + row) * 512 + k0 + scol, Bs1 + row * 64 + scol);
    }
    __syncthreads();   // compiler drains vmcnt before barrier -> LDS ready

#pragma unroll
    for (int kk = 0; kk < 2; ++kk) {
      const int kof = kk * 32 + (lane >> 4) * 8;
      const int rl = lane & 15;
      short8 av[4], b0[4], b1[4];
#pragma unroll
      for (int f = 0; f < 4; ++f)
        av[f] = *(const short8*)(As + (wm + f * 16 + rl) * 64 + kof);
#pragma unroll
      for (int g = 0; g < 4; ++g) {
        b0[g] = *(const short8*)(Bs0 + (wn + g * 16 + rl) * 64 + kof);
        b1[g] = *(const short8*)(Bs1 + (wn + g * 16 + rl) * 64 + kof);
      }
#pragma unroll
      for (int f = 0; f < 4; ++f)
#pragma unroll
        for (int g = 0; g < 4; ++g) {
          acc0[f][g] = __builtin_amdgcn_mfma_f32_16x16x32_bf16(av[f], b0[g], acc0[f][g], 0, 0, 0);
          acc1[f][g] = __builtin_amdgcn_mfma_f32_16x16x32_bf16(av[f], b1[g], acc1[f][g], 0, 0, 0);
        }
    }
  }

  // ---- fused epilogue: nonlinearity + packed store + chunk-aggregate ----
  // C/D layout: col = lane&15, row = (lane>>4)*4 + reg
  const int rl = lane & 15;
  const int q  = lane >> 4;
  const int mb = m0 + wm;             // wave row base == chunk base (CH=64)
  const int b  = mb >> 13;            // /8192
  const int c  = (mb & 8191) >> 6;    // /64

#pragma unroll
  for (int g = 0; g < 4; ++g) {
    const int i = i0 + wn + g * 16 + rl;
    float Achunk = 1.f, Vchunk = 0.f;
#pragma unroll
    for (int f = 0; f < 4; ++f) {
      float Aseg = 1.f, Vseg = 0.f;
#pragma unroll
      for (int r = 0; r < 4; ++r) {
        float h    = acc0[f][g][r];
        float gate = acc1[f][g][r];
        float e  = __expf(gate);
        float ac = __builtin_amdgcn_rcpf(1.f + e);   // sigmoid(-gate)
        float z  = e * ac;                           // sigmoid(gate)
        float gg;
        if (h >= 0.f) gg = h + 0.5f;
        else { float eh = __expf(h); gg = eh * __builtin_amdgcn_rcpf(1.f + eh); }
        float v = z * gg;
        int m = mb + f * 16 + q * 4 + r;
        avArr[(size_t)m * 1024 + i] = (uint32_t)f2bf(ac) | ((uint32_t)f2bf(v) << 16);
        // in-lane ordered fold over r (rows q*4+r ascending)
        Vseg = Vseg * ac + v;
        Aseg = Aseg * ac;
      }
      // ordered butterfly over q: step 16 (q^1), then step 32 (q^2)
      {
        float Ap = __shfl_xor(Aseg, 16);
        float Vp = __shfl_xor(Vseg, 16);
        if (q & 1) { Vseg = Vp * Aseg + Vseg; Aseg = Ap * Aseg; }
        else       { Vseg = Vseg * Ap + Vp;   Aseg = Aseg * Ap; }
      }
      {
        float Ap = __shfl_xor(Aseg, 32);
        float Vp = __shfl_xor(Vseg, 32);
        if (q & 2) { Vseg = Vp * Aseg + Vseg; Aseg = Ap * Aseg; }
        else       { Vseg = Vseg * Ap + Vp;   Aseg = Aseg * Ap; }
      }
      // sequential fold over f (rows f*16.. ascending)
      Vchunk = Vchunk * Aseg + Vseg;
      Achunk = Achunk * Aseg;
    }
    if (lane < 16) {
      size_t co = ((size_t)b * NC + c) * 1024 + i;
      Acar[co] = Achunk;
      Vcar[co] = Vchunk;
    }
  }
}

// ---------------- scan phase B: sequential carry combine over chunks ----------
__global__ void k_scanB(const float* __restrict__ hidden,
                        const float* __restrict__ Acar, const float* __restrict__ Vcar,
                        float* __restrict__ Hstart)
{
  int t = blockIdx.x * blockDim.x + threadIdx.x;  // 0..4095
  int b = t >> 10, i = t & 1023;
  float H = hidden[(size_t)b * 1024 + i];
  for (int c = 0; c < NC; ++c) {
    size_t o = ((size_t)b * NC + c) * 1024 + i;
    Hstart[o] = H;
    H = fmaf(Acar[o], H, Vcar[o]);
  }
}

// ---------------- scan phase C: re-scan with correct H, emit h_all (bf16) -----
__global__ void k_scanC(const uint32_t* __restrict__ av,
                        const float* __restrict__ Hstart,
                        unsigned short* __restrict__ hAll, float* __restrict__ nextH)
{
  int c = blockIdx.x & (NC - 1);
  int b = blockIdx.x >> 7;  // NC=128
  size_t base4 = (((size_t)b * 8192 + (size_t)c * CH) * 1024) / 4 + threadIdx.x;
  size_t ho = (((size_t)b * NC + c) * 1024) / 4 + threadIdx.x;
  float4 H = reinterpret_cast<const float4*>(Hstart)[ho];
#pragma unroll 4
  for (int t = 0; t < CH; ++t) {
    uint4 u = reinterpret_cast<const uint4*>(av)[base4 + (size_t)t * 256];
    H.x = fmaf(bf2f(u.x & 0xffffu), H.x, bf2f(u.x >> 16));
    H.y = fmaf(bf2f(u.y & 0xffffu), H.y, bf2f(u.y >> 16));
    H.z = fmaf(bf2f(u.z & 0xffffu), H.z, bf2f(u.z >> 16));
    H.w = fmaf(bf2f(u.w & 0xffffu), H.w, bf2f(u.w >> 16));
    ushort4 o = make_ushort4(f2bf(H.x), f2bf(H.y), f2bf(H.z), f2bf(H.w));
    reinterpret_cast<ushort4*>(hAll)[base4 + (size_t)t * 256] = o;
  }
  if (c == NC - 1)
    reinterpret_cast<float4*>(nextH)[(size_t)b * 256 + threadIdx.x] = H;
}

// ---------------- GEMM2: out = h_all @ W_out^T ----------------
__global__ __launch_bounds__(256, 2) void k_gemm2(
    const unsigned short* __restrict__ Ab,   // 32768 x 1024 bf16
    const unsigned short* __restrict__ Bb,   // 512 x 1024 bf16
    float* __restrict__ out)                 // 32768 x 512 f32
{
  __shared__ unsigned short As[128 * 64];
  __shared__ unsigned short Bs[128 * 64];

  const int m0 = blockIdx.y * 128;
  const int n0 = blockIdx.x * 128;
  const int tid = threadIdx.x;
  const int lane = tid & 63;
  const int wave = tid >> 6;
  const int wm = (wave >> 1) * 64;
  const int wn = (wave & 1) * 64;
  const int srow = tid >> 3;
  const int scol = (tid & 7) * 8;

  f32x4 acc[4][4];
#pragma unroll
  for (int f = 0; f < 4; ++f)
#pragma unroll
    for (int g = 0; g < 4; ++g) acc[f][g] = f32x4{0.f, 0.f, 0.f, 0.f};

  for (int k0 = 0; k0 < 1024; k0 += 64) {
    __syncthreads();
#pragma unroll
    for (int j = 0; j < 4; ++j) {
      int row = j * 32 + srow;
      GLOAD_LDS16(Ab + (size_t)(m0 + row) * 1024 + k0 + scol, As + row * 64 + scol);
    }
#pragma unroll
    for (int j = 0; j < 4; ++j) {
      int row = j * 32 + srow;
      GLOAD_LDS16(Bb + (size_t)(n0 + row) * 1024 + k0 + scol, Bs + row * 64 + scol);
    }
    __syncthreads();

#pragma unroll
    for (int kk = 0; kk < 2; ++kk) {
      const int kof = kk * 32 + (lane >> 4) * 8;
      const int rl = lane & 15;
      short8 av[4], bv[4];
#pragma unroll
      for (int f = 0; f < 4; ++f)
        av[f] = *(const short8*)(As + (wm + f * 16 + rl) * 64 + kof);
#pragma unroll
      for (int g = 0; g < 4; ++g)
        bv[g] = *(const short8*)(Bs + (wn + g * 16 + rl) * 64 + kof);
#pragma unroll
      for (int f = 0; f < 4; ++f)
#pragma unroll
        for (int g = 0; g < 4; ++g)
          acc[f][g] = __builtin_amdgcn_mfma_f32_16x16x32_bf16(av[f], bv[g], acc[f][g], 0, 0, 0);
    }
  }

  const int rl = lane & 15;
  const int rr = (lane >> 4) * 4;
#pragma unroll
  for (int f = 0; f < 4; ++f)
#pragma unroll
    for (int g = 0; g < 4; ++g)
#pragma unroll
      for (int r = 0; r < 4; ++r) {
        int m = m0 + wm + f * 16 + rr + r;
        int n = n0 + wn + g * 16 + rl;
        out[(size_t)m * 512 + n] = acc[f][g][r];
      }
}

// ---------------- driver ----------------
extern "C" void kernel_launch(void* const* d_in, const int* in_sizes, int n_in,
                              void* d_out, int out_size, void* d_ws, size_t ws_size,
                              hipStream_t stream) {
  const float* X      = (const float*)d_in[0];
  const float* hidden = (const float*)d_in[1];
  const float* W_hg   = (const float*)d_in[2];
  const float* W_out  = (const float*)d_in[3];

  float* out   = (float*)d_out;                    // (4,8192,512) f32
  float* nextH = out + (size_t)32768 * 512;        // (4,1,1024) f32

  char* ws = (char*)d_ws;
  size_t off = 0;
  auto alloc = [&](size_t bytes) -> void* {
    void* p = ws + off;
    off = (off + bytes + 255) & ~(size_t)255;
    return p;
  };
  unsigned short* Xb    = (unsigned short*)alloc(32768ULL * 512 * 2);
  unsigned short* Whgb  = (unsigned short*)alloc(2048ULL * 512 * 2);
  unsigned short* Woutb = (unsigned short*)alloc(512ULL * 1024 * 2);
  unsigned short* hAll  = (unsigned short*)alloc(32768ULL * 1024 * 2);
  float*    Acar   = (float*)alloc(4ULL * NC * 1024 * 4);
  float*    Vcar   = (float*)alloc(4ULL * NC * 1024 * 4);
  float*    Hstart = (float*)alloc(4ULL * NC * 1024 * 4);
  uint32_t* avArr  = (uint32_t*)alloc(32768ULL * 1024 * 4);

  k_f32_to_bf16<<<16384, 256, 0, stream>>>(X, Xb, 16777216 / 4);
  k_f32_to_bf16<<<1024, 256, 0, stream>>>(W_hg, Whgb, 1048576 / 4);
  k_f32_to_bf16<<<512, 256, 0, stream>>>(W_out, Woutb, 524288 / 4);

  dim3 g1(8, 256);
  k_gemm1<<<g1, 256, 0, stream>>>(Xb, Whgb, avArr, Acar, Vcar);

  k_scanB<<<16, 256, 0, stream>>>(hidden, Acar, Vcar, Hstart);
  k_scanC<<<4 * NC, 256, 0, stream>>>(avArr, Hstart, hAll, nextH);

  dim3 g2(4, 256);
  k_gemm2<<<g2, 256, 0, stream>>>(hAll, Woutb, out);
}